// Round 6
// baseline (2311.230 us; speedup 1.0000x reference)
//
#include <hip/hip_runtime.h>
#include <stdint.h>

#define AS1 __attribute__((address_space(1)))
#define AS3 __attribute__((address_space(3)))

typedef __attribute__((ext_vector_type(8))) __bf16 bf16x8;
typedef __attribute__((ext_vector_type(4))) float f32x4;
typedef __attribute__((ext_vector_type(4))) uint32_t u32x4;

__device__ __forceinline__ float b2f(uint16_t h) {
  union { uint32_t u; float f; } v; v.u = ((uint32_t)h) << 16; return v.f;
}
__device__ __forceinline__ uint16_t f2b(float f) {
  union { float f; uint32_t u; } v; v.f = f;
  uint32_t r = v.u + 0x7fffu + ((v.u >> 16) & 1u);
  return (uint16_t)(r >> 16);
}
// global->LDS async copy, 16B per lane. LDS dest is wave-uniform base + lane*16.
__device__ __forceinline__ void gload_lds16(const void* g, void* l) {
  __builtin_amdgcn_global_load_lds((AS1 void*)(uintptr_t)g, (AS3 void*)l, 16, 0, 0);
}

template <typename T> __device__ __forceinline__ void store_out(T* p, float v);
template <> __device__ __forceinline__ void store_out<uint16_t>(uint16_t* p, float v) { *p = f2b(v); }
template <> __device__ __forceinline__ void store_out<float>(float* p, float v) { *p = v; }

// ---------------- generic C = A * B^T GEMM, bf16 in, fp32 accum --------------
// A: [M x K] row stride a_stride, per-head offset a_hoff (elements)
// B: [N x K] row stride b_stride, per-head offset b_hoff   (weights as (out,in))
// C: [M x N] row stride c_stride, per-head offset c_hoff; OutT = uint16_t(bf16) or float
// tile 128x128, BK=32, 4 waves (2x2), each wave 4x4 16x16 fragments. M%128==0, K%32==0.
template <typename OutT>
__global__ __launch_bounds__(256)
void gemm_bt(const uint16_t* __restrict__ A, int a_stride, long long a_hoff,
             const uint16_t* __restrict__ B, int b_stride, long long b_hoff,
             OutT* __restrict__ C, int c_stride, long long c_hoff,
             int N, int K)
{
  __shared__ __attribute__((aligned(16))) uint16_t As[4096];
  __shared__ __attribute__((aligned(16))) uint16_t Bs[4096];
  const int tid = threadIdx.x;
  const int lane = tid & 63, w = tid >> 6;
  const int wm = w >> 1, wn = w & 1;
  const int lr = lane & 15, lg = lane >> 4;
  const int n0 = blockIdx.x * 128, m0 = blockIdx.y * 128;
  const int h = blockIdx.z;
  const uint16_t* Ag = A + (size_t)(a_hoff * h);
  const uint16_t* Bg = B + (size_t)(b_hoff * h);
  OutT* Cg = C + (size_t)(c_hoff * h);

  const int srow = w * 16 + (lane >> 2);   // staging row covered by this lane
  const int sk = (lane & 3) * 8;           // staging k offset
  uint16_t* As0 = As + w * 512;            // wave-uniform LDS bases
  uint16_t* Bs0 = Bs + w * 512;

  const size_t aoff0 = (size_t)(m0 + srow) * a_stride + sk;
  const size_t aoff1 = (size_t)(m0 + srow + 64) * a_stride + sk;
  int bn0 = n0 + srow;       if (bn0 > N - 1) bn0 = N - 1;   // clamp (partial N tile)
  int bn1 = n0 + srow + 64;  if (bn1 > N - 1) bn1 = N - 1;
  const size_t boff0 = (size_t)bn0 * b_stride + sk;
  const size_t boff1 = (size_t)bn1 * b_stride + sk;

  f32x4 acc[4][4];
  const f32x4 fzero = {0.0f, 0.0f, 0.0f, 0.0f};
#pragma unroll
  for (int i = 0; i < 4; ++i)
#pragma unroll
    for (int j = 0; j < 4; ++j) acc[i][j] = fzero;

  for (int k0 = 0; k0 < K; k0 += 32) {
    gload_lds16(Ag + aoff0 + k0, As0);
    gload_lds16(Ag + aoff1 + k0, As0 + 2048);
    gload_lds16(Bg + boff0 + k0, Bs0);
    gload_lds16(Bg + boff1 + k0, Bs0 + 2048);
    __syncthreads();
    bf16x8 af[4], bfr[4];
#pragma unroll
    for (int mt = 0; mt < 4; ++mt)
      af[mt] = *(const bf16x8*)(As + (wm * 64 + mt * 16 + lr) * 32 + lg * 8);
#pragma unroll
    for (int nt = 0; nt < 4; ++nt)
      bfr[nt] = *(const bf16x8*)(Bs + (wn * 64 + nt * 16 + lr) * 32 + lg * 8);
#pragma unroll
    for (int mt = 0; mt < 4; ++mt)
#pragma unroll
      for (int nt = 0; nt < 4; ++nt)
        acc[mt][nt] = __builtin_amdgcn_mfma_f32_16x16x32_bf16(af[mt], bfr[nt], acc[mt][nt], 0, 0, 0);
    __syncthreads();
  }

  // C/D layout (HW-verified): row_in_tile = (lane>>4)*4 + reg, col_in_tile = lane&15
#pragma unroll
  for (int mt = 0; mt < 4; ++mt) {
    const int mbase = m0 + wm * 64 + mt * 16 + lg * 4;
#pragma unroll
    for (int nt = 0; nt < 4; ++nt) {
      const int n = n0 + wn * 64 + nt * 16 + lr;
      if (n < N) {
#pragma unroll
        for (int r = 0; r < 4; ++r)
          store_out(&Cg[(size_t)(mbase + r) * c_stride + n], acc[mt][nt][r]);
      }
    }
  }
}

// ---------------- fp32 -> bf16 convert (x4 per thread) ------------------------
__global__ void cvt_bf16(const float* __restrict__ in, uint16_t* __restrict__ out, int n4)
{
  int i = blockIdx.x * blockDim.x + threadIdx.x;
  if (i < n4) {
    f32x4 v = *(const f32x4*)(in + (size_t)i * 4);
    union { uint64_t u; uint16_t s[4]; } o;
    o.s[0] = f2b(v[0]); o.s[1] = f2b(v[1]); o.s[2] = f2b(v[2]); o.s[3] = f2b(v[3]);
    *(uint64_t*)(out + (size_t)i * 4) = o.u;
  }
}

// ---------------- wn_t[h][c][d] = bf16(wkv_b[h*256+d][c]) --------------------
__global__ void build_wnt(const float* __restrict__ wkv_b, uint16_t* __restrict__ wn_t)
{
  int idx = blockIdx.x * 256 + threadIdx.x;   // 16*128*512 = 1048576
  int c = idx & 511, d = (idx >> 9) & 127, h = idx >> 16;
  wn_t[(size_t)((h * 512 + c) << 7) + d] = f2b(wkv_b[(size_t)((h * 256 + d) << 9) + c]);
}

// ---------------- RoPE on q_pe: q_buf -> q_lat[...,512:576] ------------------
__global__ void rope_q(const uint16_t* __restrict__ q_buf, const float* __restrict__ fcos,
                       const float* __restrict__ fsin, uint16_t* __restrict__ q_lat)
{
  int idx = blockIdx.x * 256 + threadIdx.x;   // 4096*16*32
  int i = idx & 31, h = (idx >> 5) & 15, row = idx >> 9;
  int s = row & 2047;
  uint32_t raw = *(const uint32_t*)(q_buf + (size_t)row * 3072 + h * 192 + 128 + 2 * i);
  float x0 = b2f((uint16_t)(raw & 0xffff)), x1 = b2f((uint16_t)(raw >> 16));
  float c = fcos[s * 32 + i], sn = fsin[s * 32 + i];
  uint16_t o0 = f2b(x0 * c - x1 * sn), o1 = f2b(x0 * sn + x1 * c);
  *(uint32_t*)(q_lat + ((size_t)row * 16 + h) * 576 + 512 + 2 * i) = (uint32_t)o0 | ((uint32_t)o1 << 16);
}

// ------- rmsnorm(kv)->k_lat[:512] & v_t (transposed), rope(k_pe)->k_lat[512:] -
__global__ __launch_bounds__(256)
void kv_build(const uint16_t* __restrict__ kv_buf, const float* __restrict__ kv_norm_w,
              const float* __restrict__ fcos, const float* __restrict__ fsin,
              uint16_t* __restrict__ k_lat, uint16_t* __restrict__ v_t)
{
  __shared__ __attribute__((aligned(16))) uint16_t tile[64][520];
  const int tid = threadIdx.x, w = tid >> 6, lane = tid & 63;
  const int r0 = blockIdx.x * 64;              // global token row base
  // phase 1: per-wave rows, rmsnorm + rope
  for (int i = 0; i < 16; ++i) {
    const int rl = w * 16 + i;
    const int row = r0 + rl;
    const int s = row & 2047;
    const uint16_t* src = kv_buf + (size_t)row * 576;
    u32x4 raw = *(const u32x4*)(src + lane * 8);
    const uint16_t* rp = (const uint16_t*)&raw;
    float v[8]; float ss = 0.0f;
#pragma unroll
    for (int j = 0; j < 8; ++j) { v[j] = b2f(rp[j]); ss += v[j] * v[j]; }
#pragma unroll
    for (int off = 1; off < 64; off <<= 1) ss += __shfl_xor(ss, off);
    const float rs = rsqrtf(ss * (1.0f / 512.0f) + 1e-6f);
    union { u32x4 vec; uint16_t s16[8]; } ov;
#pragma unroll
    for (int j = 0; j < 8; ++j) {
      uint16_t cv = f2b(v[j] * rs * kv_norm_w[lane * 8 + j]);
      ov.s16[j] = cv;
      tile[rl][lane * 8 + j] = cv;
    }
    *(u32x4*)(k_lat + (size_t)row * 576 + lane * 8) = ov.vec;
    if (lane < 32) {
      float x0 = b2f(src[512 + 2 * lane]);
      float x1 = b2f(src[512 + 2 * lane + 1]);
      float c = fcos[s * 32 + lane], sn = fsin[s * 32 + lane];
      uint16_t o0 = f2b(x0 * c - x1 * sn), o1 = f2b(x0 * sn + x1 * c);
      *(uint32_t*)(k_lat + (size_t)row * 576 + 512 + 2 * lane) = (uint32_t)o0 | ((uint32_t)o1 << 16);
    }
  }
  __syncthreads();
  // phase 2: transposed write v_t[b][c][s]
  const int b = r0 >> 11, s0 = r0 & 2047;
  for (int it = 0; it < 16; ++it) {
    int idx = it * 256 + tid;                 // 512 c * 8 groups
    int c = idx >> 3, g = idx & 7;
    union { u32x4 vec; uint16_t s16[8]; } tmp;
#pragma unroll
    for (int j = 0; j < 8; ++j) tmp.s16[j] = tile[g * 8 + j][c];
    *(u32x4*)(v_t + ((size_t)(b * 512 + c)) * 2048 + s0 + g * 8) = tmp.vec;
  }
}

// ---------------- flash attention -------------------------------------------
// grid (32 qtiles, 32 b*h); block 256 = 4 waves, each wave owns 16 q rows.
__global__ __launch_bounds__(256, 2)
void flash_attn(const uint16_t* __restrict__ q_lat, const uint16_t* __restrict__ k_lat,
                const uint16_t* __restrict__ v_t, uint16_t* __restrict__ o_head)
{
  __shared__ __attribute__((aligned(16))) uint16_t Qs[64 * 584];
  __shared__ __attribute__((aligned(16))) uint16_t Ps[4 * 16 * 56];
  const int tid = threadIdx.x;
  const int lane = tid & 63, w = tid >> 6;
  const int lr = lane & 15, lg = lane >> 4;
  const int q0 = blockIdx.x * 64;
  const int bh = blockIdx.y;
  const int b = bh >> 4, h = bh & 15;

  // stage Q tile (64 x 576) into LDS (row stride 584 to dodge bank conflicts)
  for (int it = 0; it < 18; ++it) {
    int chunk = it * 256 + tid;               // 4608 chunks of 8 elems
    int row = chunk / 72, col = (chunk % 72) * 8;
    u32x4 d = *(const u32x4*)(q_lat + ((size_t)((b * 2048 + q0 + row) * 16 + h)) * 576 + col);
    *(u32x4*)(Qs + row * 584 + col) = d;
  }
  __syncthreads();

  float m_r[4], l_r[4];
#pragma unroll
  for (int r = 0; r < 4; ++r) { m_r[r] = -1e30f; l_r[r] = 0.0f; }
  const f32x4 fzero = {0.0f, 0.0f, 0.0f, 0.0f};
  f32x4 o_acc[32];
#pragma unroll
  for (int n = 0; n < 32; ++n) o_acc[n] = fzero;

  const size_t kb = (size_t)b * 2048 * 576;
  const size_t vb = (size_t)b * 512 * 2048;
  uint16_t* Pw = Ps + w * 16 * 56;
  const float scale = 0.07216878364870323f;   // 192^-0.5

  for (int t0 = 0; t0 < 2048; t0 += 32) {
    f32x4 s0 = fzero, s1 = fzero;
#pragma unroll
    for (int kk = 0; kk < 18; ++kk) {
      bf16x8 aq = *(const bf16x8*)(Qs + (w * 16 + lr) * 584 + kk * 32 + lg * 8);
      bf16x8 k0f = *(const bf16x8*)(k_lat + kb + (size_t)(t0 + lr) * 576 + kk * 32 + lg * 8);
      bf16x8 k1f = *(const bf16x8*)(k_lat + kb + (size_t)(t0 + 16 + lr) * 576 + kk * 32 + lg * 8);
      s0 = __builtin_amdgcn_mfma_f32_16x16x32_bf16(aq, k0f, s0, 0, 0, 0);
      s1 = __builtin_amdgcn_mfma_f32_16x16x32_bf16(aq, k1f, s1, 0, 0, 0);
    }
    float alpha[4];
#pragma unroll
    for (int r = 0; r < 4; ++r) {
      float v0 = s0[r] * scale, v1 = s1[r] * scale;
      float mx = fmaxf(v0, v1);
      mx = fmaxf(mx, __shfl_xor(mx, 1));
      mx = fmaxf(mx, __shfl_xor(mx, 2));
      mx = fmaxf(mx, __shfl_xor(mx, 4));
      mx = fmaxf(mx, __shfl_xor(mx, 8));
      float mn = fmaxf(m_r[r], mx);
      float a = __expf(m_r[r] - mn);
      float p0 = __expf(v0 - mn);
      float p1 = __expf(v1 - mn);
      m_r[r] = mn; alpha[r] = a;
      float ps = p0 + p1;
      ps += __shfl_xor(ps, 1); ps += __shfl_xor(ps, 2);
      ps += __shfl_xor(ps, 4); ps += __shfl_xor(ps, 8);
      l_r[r] = l_r[r] * a + ps;
      Pw[(lg * 4 + r) * 56 + lr] = f2b(p0);
      Pw[(lg * 4 + r) * 56 + 16 + lr] = f2b(p1);
    }
#pragma unroll
    for (int n = 0; n < 32; ++n) {
#pragma unroll
      for (int r = 0; r < 4; ++r) o_acc[n][r] *= alpha[r];
    }
    asm volatile("s_waitcnt lgkmcnt(0)" ::: "memory");
    __builtin_amdgcn_sched_barrier(0);
    bf16x8 pa = *(const bf16x8*)(Pw + lr * 56 + lg * 8);
#pragma unroll
    for (int n = 0; n < 32; ++n) {
      bf16x8 bv = *(const bf16x8*)(v_t + vb + (size_t)(n * 16 + lr) * 2048 + t0 + lg * 8);
      o_acc[n] = __builtin_amdgcn_mfma_f32_16x16x32_bf16(pa, bv, o_acc[n], 0, 0, 0);
    }
  }

#pragma unroll
  for (int r = 0; r < 4; ++r) {
    float inv = 1.0f / l_r[r];
#pragma unroll
    for (int n = 0; n < 32; ++n) o_acc[n][r] *= inv;
  }
  const size_t ob = ((size_t)((b * 2048 + q0 + w * 16) * 16 + h)) * 512;
#pragma unroll
  for (int n = 0; n < 32; ++n)
#pragma unroll
    for (int r = 0; r < 4; ++r)
      o_head[ob + (size_t)(lg * 4 + r) * 8192 + n * 16 + lr] = f2b(o_acc[n][r]);
}

// ---------------------------------------------------------------------------
extern "C" void kernel_launch(void* const* d_in, const int* in_sizes, int n_in,
                              void* d_out, int out_size, void* d_ws, size_t ws_size,
                              hipStream_t stream)
{
  const float* x     = (const float*)d_in[0];
  // d_in[1] = start_pos (0, unused)
  const float* fcos  = (const float*)d_in[2];
  const float* fsin  = (const float*)d_in[3];
  const float* wq    = (const float*)d_in[4];
  const float* wkv_a = (const float*)d_in[5];
  const float* kvnw  = (const float*)d_in[6];
  const float* wkv_b = (const float*)d_in[7];
  const float* wo    = (const float*)d_in[8];
  float* out = (float*)d_out;   // reference output dtype is float32

  char* ws = (char*)d_ws;
  auto alloc = [&](size_t bytes) { char* p = ws; ws += (bytes + 255) & ~(size_t)255; return p; };
  uint16_t* xb     = (uint16_t*)alloc(4096ull * 2048 * 2);
  uint16_t* wq_b   = (uint16_t*)alloc(3072ull * 2048 * 2);
  uint16_t* wkva_b = (uint16_t*)alloc(576ull * 2048 * 2);
  uint16_t* wkvb_b = (uint16_t*)alloc(4096ull * 512 * 2);
  uint16_t* wo_b   = (uint16_t*)alloc(2048ull * 2048 * 2);
  uint16_t* wn_t   = (uint16_t*)alloc(16ull * 512 * 128 * 2);
  uint16_t* q_buf  = (uint16_t*)alloc(4096ull * 3072 * 2);
  uint16_t* kv_buf = (uint16_t*)alloc(4096ull * 576 * 2);
  uint16_t* q_lat  = (uint16_t*)alloc(4096ull * 16 * 576 * 2);
  uint16_t* k_lat  = (uint16_t*)alloc(4096ull * 576 * 2);
  uint16_t* v_t    = (uint16_t*)alloc(2ull * 512 * 2048 * 2);
  uint16_t* o_head = (uint16_t*)alloc(4096ull * 16 * 512 * 2);
  uint16_t* o2     = (uint16_t*)alloc(4096ull * 2048 * 2);

  cvt_bf16<<<8192, 256, 0, stream>>>(x, xb, 2097152);
  cvt_bf16<<<6144, 256, 0, stream>>>(wq, wq_b, 1572864);
  cvt_bf16<<<1152, 256, 0, stream>>>(wkv_a, wkva_b, 294912);
  cvt_bf16<<<2048, 256, 0, stream>>>(wkv_b, wkvb_b, 524288);
  cvt_bf16<<<4096, 256, 0, stream>>>(wo, wo_b, 1048576);
  build_wnt<<<4096, 256, 0, stream>>>(wkv_b, wn_t);

  // q = x @ wq^T  -> q_buf [4096 x 3072]
  gemm_bt<uint16_t><<<dim3(24, 32, 1), 256, 0, stream>>>(xb, 2048, 0, wq_b, 2048, 0, q_buf, 3072, 0, 3072, 2048);
  // kv_full = x @ wkv_a^T -> kv_buf [4096 x 576]
  gemm_bt<uint16_t><<<dim3(5, 32, 1), 256, 0, stream>>>(xb, 2048, 0, wkva_b, 2048, 0, kv_buf, 576, 0, 576, 2048);

  rope_q<<<8192, 256, 0, stream>>>(q_buf, fcos, fsin, q_lat);
  kv_build<<<64, 256, 0, stream>>>(kv_buf, kvnw, fcos, fsin, k_lat, v_t);

  // q_abs per head: q_nope @ wkv_b_nope^T -> q_lat[..., :512]
  gemm_bt<uint16_t><<<dim3(4, 32, 16), 256, 0, stream>>>(q_buf, 3072, 192, wn_t, 128, 65536,
                                                         q_lat, 9216, 576, 512, 128);

  flash_attn<<<dim3(32, 32), 256, 0, stream>>>(q_lat, k_lat, v_t, o_head);

  // o2 per head: o_head @ wkv_b_v^T -> o2 [4096 x 2048]
  gemm_bt<uint16_t><<<dim3(1, 32, 16), 256, 0, stream>>>(o_head, 8192, 512, wkvb_b + 65536, 512, 131072,
                                                         o2, 2048, 128, 128, 512);
  // out = o2 @ wo^T (fp32 output)
  gemm_bt<float><<<dim3(16, 32, 1), 256, 0, stream>>>(o2, 2048, 0, wo_b, 2048, 0, out, 2048, 0, 2048, 2048);
}

// Round 8
// 1164.678 us; speedup vs baseline: 1.9844x; 1.9844x over previous
//
#include <hip/hip_runtime.h>
#include <stdint.h>

#define AS1 __attribute__((address_space(1)))
#define AS3 __attribute__((address_space(3)))

typedef __attribute__((ext_vector_type(8))) __bf16 bf16x8;
typedef __attribute__((ext_vector_type(4))) float f32x4;
typedef __attribute__((ext_vector_type(4))) uint32_t u32x4;

__device__ __forceinline__ float b2f(uint16_t h) {
  union { uint32_t u; float f; } v; v.u = ((uint32_t)h) << 16; return v.f;
}
__device__ __forceinline__ uint16_t f2b(float f) {
  union { float f; uint32_t u; } v; v.f = f;
  uint32_t r = v.u + 0x7fffu + ((v.u >> 16) & 1u);
  return (uint16_t)(r >> 16);
}
// global->LDS async copy, 16B per lane. LDS dest is wave-uniform base + lane*16.
__device__ __forceinline__ void gload_lds16(const void* g, void* l) {
  __builtin_amdgcn_global_load_lds((AS1 void*)(uintptr_t)g, (AS3 void*)l, 16, 0, 0);
}

template <typename T> __device__ __forceinline__ void store_out(T* p, float v);
template <> __device__ __forceinline__ void store_out<uint16_t>(uint16_t* p, float v) { *p = f2b(v); }
template <> __device__ __forceinline__ void store_out<float>(float* p, float v) { *p = v; }

// ---------------- generic C = A * B^T GEMM, bf16 in, fp32 accum --------------
template <typename OutT>
__global__ __launch_bounds__(256)
void gemm_bt(const uint16_t* __restrict__ A, int a_stride, long long a_hoff,
             const uint16_t* __restrict__ B, int b_stride, long long b_hoff,
             OutT* __restrict__ C, int c_stride, long long c_hoff,
             int N, int K)
{
  __shared__ __attribute__((aligned(16))) uint16_t As[4096];
  __shared__ __attribute__((aligned(16))) uint16_t Bs[4096];
  const int tid = threadIdx.x;
  const int lane = tid & 63, w = tid >> 6;
  const int wm = w >> 1, wn = w & 1;
  const int lr = lane & 15, lg = lane >> 4;
  const int n0 = blockIdx.x * 128, m0 = blockIdx.y * 128;
  const int h = blockIdx.z;
  const uint16_t* Ag = A + (size_t)(a_hoff * h);
  const uint16_t* Bg = B + (size_t)(b_hoff * h);
  OutT* Cg = C + (size_t)(c_hoff * h);

  const int srow = w * 16 + (lane >> 2);
  const int sk = (lane & 3) * 8;
  uint16_t* As0 = As + w * 512;
  uint16_t* Bs0 = Bs + w * 512;

  const size_t aoff0 = (size_t)(m0 + srow) * a_stride + sk;
  const size_t aoff1 = (size_t)(m0 + srow + 64) * a_stride + sk;
  int bn0 = n0 + srow;       if (bn0 > N - 1) bn0 = N - 1;
  int bn1 = n0 + srow + 64;  if (bn1 > N - 1) bn1 = N - 1;
  const size_t boff0 = (size_t)bn0 * b_stride + sk;
  const size_t boff1 = (size_t)bn1 * b_stride + sk;

  f32x4 acc[4][4];
  const f32x4 fzero = {0.0f, 0.0f, 0.0f, 0.0f};
#pragma unroll
  for (int i = 0; i < 4; ++i)
#pragma unroll
    for (int j = 0; j < 4; ++j) acc[i][j] = fzero;

  for (int k0 = 0; k0 < K; k0 += 32) {
    gload_lds16(Ag + aoff0 + k0, As0);
    gload_lds16(Ag + aoff1 + k0, As0 + 2048);
    gload_lds16(Bg + boff0 + k0, Bs0);
    gload_lds16(Bg + boff1 + k0, Bs0 + 2048);
    __syncthreads();
    bf16x8 af[4], bfr[4];
#pragma unroll
    for (int mt = 0; mt < 4; ++mt)
      af[mt] = *(const bf16x8*)(As + (wm * 64 + mt * 16 + lr) * 32 + lg * 8);
#pragma unroll
    for (int nt = 0; nt < 4; ++nt)
      bfr[nt] = *(const bf16x8*)(Bs + (wn * 64 + nt * 16 + lr) * 32 + lg * 8);
#pragma unroll
    for (int mt = 0; mt < 4; ++mt)
#pragma unroll
      for (int nt = 0; nt < 4; ++nt)
        acc[mt][nt] = __builtin_amdgcn_mfma_f32_16x16x32_bf16(af[mt], bfr[nt], acc[mt][nt], 0, 0, 0);
    __syncthreads();
  }

#pragma unroll
  for (int mt = 0; mt < 4; ++mt) {
    const int mbase = m0 + wm * 64 + mt * 16 + lg * 4;
#pragma unroll
    for (int nt = 0; nt < 4; ++nt) {
      const int n = n0 + wn * 64 + nt * 16 + lr;
      if (n < N) {
#pragma unroll
        for (int r = 0; r < 4; ++r)
          store_out(&Cg[(size_t)(mbase + r) * c_stride + n], acc[mt][nt][r]);
      }
    }
  }
}

// ---------------- fp32 -> bf16 convert (x4 per thread) ------------------------
__global__ void cvt_bf16(const float* __restrict__ in, uint16_t* __restrict__ out, int n4)
{
  int i = blockIdx.x * blockDim.x + threadIdx.x;
  if (i < n4) {
    f32x4 v = *(const f32x4*)(in + (size_t)i * 4);
    union { uint64_t u; uint16_t s[4]; } o;
    o.s[0] = f2b(v[0]); o.s[1] = f2b(v[1]); o.s[2] = f2b(v[2]); o.s[3] = f2b(v[3]);
    *(uint64_t*)(out + (size_t)i * 4) = o.u;
  }
}

// ---------------- wn_t[h][c][d] = bf16(wkv_b[h*256+d][c]) --------------------
__global__ void build_wnt(const float* __restrict__ wkv_b, uint16_t* __restrict__ wn_t)
{
  int idx = blockIdx.x * 256 + threadIdx.x;
  int c = idx & 511, d = (idx >> 9) & 127, h = idx >> 16;
  wn_t[(size_t)((h * 512 + c) << 7) + d] = f2b(wkv_b[(size_t)((h * 256 + d) << 9) + c]);
}

// ---------------- RoPE on q_pe: q_buf -> q_lat[...,512:576] ------------------
__global__ void rope_q(const uint16_t* __restrict__ q_buf, const float* __restrict__ fcos,
                       const float* __restrict__ fsin, uint16_t* __restrict__ q_lat)
{
  int idx = blockIdx.x * 256 + threadIdx.x;
  int i = idx & 31, h = (idx >> 5) & 15, row = idx >> 9;
  int s = row & 2047;
  uint32_t raw = *(const uint32_t*)(q_buf + (size_t)row * 3072 + h * 192 + 128 + 2 * i);
  float x0 = b2f((uint16_t)(raw & 0xffff)), x1 = b2f((uint16_t)(raw >> 16));
  float c = fcos[s * 32 + i], sn = fsin[s * 32 + i];
  uint16_t o0 = f2b(x0 * c - x1 * sn), o1 = f2b(x0 * sn + x1 * c);
  *(uint32_t*)(q_lat + ((size_t)row * 16 + h) * 576 + 512 + 2 * i) = (uint32_t)o0 | ((uint32_t)o1 << 16);
}

// ------- rmsnorm(kv)->k_lat[:512] & v_t (transposed), rope(k_pe)->k_lat[512:] -
__global__ __launch_bounds__(256)
void kv_build(const uint16_t* __restrict__ kv_buf, const float* __restrict__ kv_norm_w,
              const float* __restrict__ fcos, const float* __restrict__ fsin,
              uint16_t* __restrict__ k_lat, uint16_t* __restrict__ v_t)
{
  __shared__ __attribute__((aligned(16))) uint16_t tile[64][520];
  const int tid = threadIdx.x, w = tid >> 6, lane = tid & 63;
  const int r0 = blockIdx.x * 64;
  for (int i = 0; i < 16; ++i) {
    const int rl = w * 16 + i;
    const int row = r0 + rl;
    const int s = row & 2047;
    const uint16_t* src = kv_buf + (size_t)row * 576;
    u32x4 raw = *(const u32x4*)(src + lane * 8);
    const uint16_t* rp = (const uint16_t*)&raw;
    float v[8]; float ss = 0.0f;
#pragma unroll
    for (int j = 0; j < 8; ++j) { v[j] = b2f(rp[j]); ss += v[j] * v[j]; }
#pragma unroll
    for (int off = 1; off < 64; off <<= 1) ss += __shfl_xor(ss, off);
    const float rs = rsqrtf(ss * (1.0f / 512.0f) + 1e-6f);
    union { u32x4 vec; uint16_t s16[8]; } ov;
#pragma unroll
    for (int j = 0; j < 8; ++j) {
      uint16_t cv = f2b(v[j] * rs * kv_norm_w[lane * 8 + j]);
      ov.s16[j] = cv;
      tile[rl][lane * 8 + j] = cv;
    }
    *(u32x4*)(k_lat + (size_t)row * 576 + lane * 8) = ov.vec;
    if (lane < 32) {
      float x0 = b2f(src[512 + 2 * lane]);
      float x1 = b2f(src[512 + 2 * lane + 1]);
      float c = fcos[s * 32 + lane], sn = fsin[s * 32 + lane];
      uint16_t o0 = f2b(x0 * c - x1 * sn), o1 = f2b(x0 * sn + x1 * c);
      *(uint32_t*)(k_lat + (size_t)row * 576 + 512 + 2 * lane) = (uint32_t)o0 | ((uint32_t)o1 << 16);
    }
  }
  __syncthreads();
  const int b = r0 >> 11, s0 = r0 & 2047;
  for (int it = 0; it < 16; ++it) {
    int idx = it * 256 + tid;
    int c = idx >> 3, g = idx & 7;
    union { u32x4 vec; uint16_t s16[8]; } tmp;
#pragma unroll
    for (int j = 0; j < 8; ++j) tmp.s16[j] = tile[g * 8 + j][c];
    *(u32x4*)(v_t + ((size_t)(b * 512 + c)) * 2048 + s0 + g * 8) = tmp.vec;
  }
}

// ---------------- fragment-order repack of K and V^T per 32-token tile -------
// k_f[b][tile][kk][half][lg][lr][8] : 2304 16B units = 36KB per tile
// v_f[b][tile][n ][lg][lr][8]       : 2048 16B units = 32KB per tile
// A linear copy of one tile into LDS makes every ds_read_b128 (64 lanes,
// contiguous 1024B) bank-conflict-free.
__global__ void repack_kv(const uint16_t* __restrict__ k_lat, const uint16_t* __restrict__ v_t,
                          uint16_t* __restrict__ k_f, uint16_t* __restrict__ v_f)
{
  const int blk = blockIdx.x;            // b*64 + tile
  const int b = blk >> 6, tile = blk & 63;
  const int tid = threadIdx.x;
  for (int u = tid; u < 2304; u += 256) {
    int lr = u & 15, lg = (u >> 4) & 3, kh = u >> 6;   // kh = kk*2+half
    int kk = kh >> 1, half = kh & 1;
    int row = b * 2048 + tile * 32 + half * 16 + lr;
    u32x4 d = *(const u32x4*)(k_lat + (size_t)row * 576 + kk * 32 + lg * 8);
    *(u32x4*)(k_f + (size_t)blk * 18432 + u * 8) = d;
  }
  for (int u = tid; u < 2048; u += 256) {
    int lr = u & 15, lg = (u >> 4) & 3, n = u >> 6;
    int c = n * 16 + lr;
    u32x4 d = *(const u32x4*)(v_t + ((size_t)(b * 512 + c)) * 2048 + tile * 32 + lg * 8);
    *(u32x4*)(v_f + (size_t)blk * 16384 + u * 8) = d;
  }
}

// ---------------- flash attention v2 -----------------------------------------
// grid (16 qtiles of 128, 32 b*h); 512 threads = 8 waves, wave owns 16 q rows.
// Q in registers; K/V tiles double-buffered in LDS, staged by all 8 waves.
__global__ __launch_bounds__(512, 2)
void flash_attn2(const uint16_t* __restrict__ q_lat, const uint16_t* __restrict__ k_f,
                 const uint16_t* __restrict__ v_f, uint16_t* __restrict__ o_head)
{
  __shared__ __attribute__((aligned(16))) uint16_t Kt[2][18432];
  __shared__ __attribute__((aligned(16))) uint16_t Vt[2][16384];
  __shared__ __attribute__((aligned(16))) uint16_t Ps[8][896];
  const int tid = threadIdx.x;
  const int lane = tid & 63, w = tid >> 6;
  const int lr = lane & 15, lg = lane >> 4;
  const int q0 = blockIdx.x * 128;
  const int bh = blockIdx.y;
  const int b = bh >> 4, h = bh & 15;

  // Q rows of this wave -> registers (18 x bf16x8 = 72 VGPR)
  bf16x8 aq[18];
  const uint16_t* qrow = q_lat + ((size_t)((b * 2048 + q0 + w * 16 + lr) * 16 + h)) * 576;
#pragma unroll
  for (int kk = 0; kk < 18; ++kk) aq[kk] = *(const bf16x8*)(qrow + kk * 32 + lg * 8);

  const uint16_t* kfb = k_f + (size_t)b * 64 * 18432;
  const uint16_t* vfb = v_f + (size_t)b * 64 * 16384;

  float m_r[4], l_r[4];
#pragma unroll
  for (int r = 0; r < 4; ++r) { m_r[r] = -1e30f; l_r[r] = 0.0f; }
  const f32x4 fzero = {0.0f, 0.0f, 0.0f, 0.0f};
  f32x4 o_acc[32];
#pragma unroll
  for (int n = 0; n < 32; ++n) o_acc[n] = fzero;

  uint16_t* Pw = Ps[w];
  const float scale = 0.07216878364870323f;   // 192^-0.5

  // cooperative stage of one tile: waves 0-3 -> K (9 issues), waves 4-7 -> V (8)
  auto stage = [&](int t, int buf) {
    const uint16_t* kt = kfb + (size_t)t * 18432;
    const uint16_t* vt = vfb + (size_t)t * 16384;
    if (w < 4) {
#pragma unroll
      for (int i = 0; i < 9; ++i) {
        int u = (w * 9 + i) * 512;                    // elements (1024B units)
        gload_lds16(kt + u + lane * 8, &Kt[buf][u]);
      }
    } else {
#pragma unroll
      for (int i = 0; i < 8; ++i) {
        int u = ((w - 4) * 8 + i) * 512;
        gload_lds16(vt + u + lane * 8, &Vt[buf][u]);
      }
    }
  };

  stage(0, 0);
  __syncthreads();                                    // drains vmcnt before barrier

  int cur = 0;
  for (int t = 0; t < 64; ++t) {
    if (t + 1 < 64) stage(t + 1, cur ^ 1);            // async prefetch next tile

    // QK^T over 576 dims: s0 = S[q][t0+lr], s1 = S[q][t0+16+lr]
    f32x4 s0 = fzero, s1 = fzero;
    const uint16_t* kb = Kt[cur];
#pragma unroll
    for (int kk = 0; kk < 18; ++kk) {
      bf16x8 k0 = *(const bf16x8*)(kb + (kk * 2) * 512 + lane * 8);
      bf16x8 k1 = *(const bf16x8*)(kb + (kk * 2 + 1) * 512 + lane * 8);
      s0 = __builtin_amdgcn_mfma_f32_16x16x32_bf16(aq[kk], k0, s0, 0, 0, 0);
      s1 = __builtin_amdgcn_mfma_f32_16x16x32_bf16(aq[kk], k1, s1, 0, 0, 0);
    }

    float alpha[4];
#pragma unroll
    for (int r = 0; r < 4; ++r) {
      float v0 = s0[r] * scale, v1 = s1[r] * scale;
      float mx = fmaxf(v0, v1);
      mx = fmaxf(mx, __shfl_xor(mx, 1));
      mx = fmaxf(mx, __shfl_xor(mx, 2));
      mx = fmaxf(mx, __shfl_xor(mx, 4));
      mx = fmaxf(mx, __shfl_xor(mx, 8));
      float mn = fmaxf(m_r[r], mx);
      float a = __expf(m_r[r] - mn);
      float p0 = __expf(v0 - mn);
      float p1 = __expf(v1 - mn);
      m_r[r] = mn; alpha[r] = a;
      float ps = p0 + p1;
      ps += __shfl_xor(ps, 1); ps += __shfl_xor(ps, 2);
      ps += __shfl_xor(ps, 4); ps += __shfl_xor(ps, 8);
      l_r[r] = l_r[r] * a + ps;
      Pw[(lg * 4 + r) * 56 + lr] = f2b(p0);
      Pw[(lg * 4 + r) * 56 + 16 + lr] = f2b(p1);
    }
#pragma unroll
    for (int n = 0; n < 32; ++n) {
#pragma unroll
      for (int r = 0; r < 4; ++r) o_acc[n][r] *= alpha[r];
    }
    asm volatile("s_waitcnt lgkmcnt(0)" ::: "memory");
    __builtin_amdgcn_sched_barrier(0);
    bf16x8 pa = *(const bf16x8*)(Pw + lr * 56 + lg * 8);

    // PV: 32 independent accumulators, conflict-free contiguous ds_reads
    const uint16_t* vbuf = Vt[cur];
#pragma unroll
    for (int n = 0; n < 32; ++n) {
      bf16x8 bv = *(const bf16x8*)(vbuf + n * 512 + lane * 8);
      o_acc[n] = __builtin_amdgcn_mfma_f32_16x16x32_bf16(pa, bv, o_acc[n], 0, 0, 0);
    }

    __syncthreads();                                  // drains stage vmcnt + ds ops
    cur ^= 1;
  }

#pragma unroll
  for (int r = 0; r < 4; ++r) {
    float inv = 1.0f / l_r[r];
#pragma unroll
    for (int n = 0; n < 32; ++n) o_acc[n][r] *= inv;
  }
  const size_t ob = ((size_t)((b * 2048 + q0 + w * 16) * 16 + h)) * 512;
#pragma unroll
  for (int n = 0; n < 32; ++n)
#pragma unroll
    for (int r = 0; r < 4; ++r)
      o_head[ob + (size_t)(lg * 4 + r) * 8192 + n * 16 + lr] = f2b(o_acc[n][r]);
}

// ---------------------------------------------------------------------------
extern "C" void kernel_launch(void* const* d_in, const int* in_sizes, int n_in,
                              void* d_out, int out_size, void* d_ws, size_t ws_size,
                              hipStream_t stream)
{
  const float* x     = (const float*)d_in[0];
  const float* fcos  = (const float*)d_in[2];
  const float* fsin  = (const float*)d_in[3];
  const float* wq    = (const float*)d_in[4];
  const float* wkv_a = (const float*)d_in[5];
  const float* kvnw  = (const float*)d_in[6];
  const float* wkv_b = (const float*)d_in[7];
  const float* wo    = (const float*)d_in[8];
  float* out = (float*)d_out;   // reference output dtype is float32

  char* ws = (char*)d_ws;
  auto alloc = [&](size_t bytes) { char* p = ws; ws += (bytes + 255) & ~(size_t)255; return p; };
  uint16_t* xb     = (uint16_t*)alloc(4096ull * 2048 * 2);
  uint16_t* wq_b   = (uint16_t*)alloc(3072ull * 2048 * 2);
  uint16_t* wkva_b = (uint16_t*)alloc(576ull * 2048 * 2);
  uint16_t* wkvb_b = (uint16_t*)alloc(4096ull * 512 * 2);
  uint16_t* wo_b   = (uint16_t*)alloc(2048ull * 2048 * 2);
  uint16_t* wn_t   = (uint16_t*)alloc(16ull * 512 * 128 * 2);
  uint16_t* q_buf  = (uint16_t*)alloc(4096ull * 3072 * 2);
  uint16_t* kv_buf = (uint16_t*)alloc(4096ull * 576 * 2);
  uint16_t* q_lat  = (uint16_t*)alloc(4096ull * 16 * 576 * 2);
  uint16_t* k_lat  = (uint16_t*)alloc(4096ull * 576 * 2);
  uint16_t* v_t    = (uint16_t*)alloc(2ull * 512 * 2048 * 2);
  uint16_t* k_f    = (uint16_t*)alloc(2ull * 64 * 18432 * 2);
  uint16_t* v_f    = (uint16_t*)alloc(2ull * 64 * 16384 * 2);
  uint16_t* o_head = (uint16_t*)alloc(4096ull * 16 * 512 * 2);
  uint16_t* o2     = (uint16_t*)alloc(4096ull * 2048 * 2);

  cvt_bf16<<<8192, 256, 0, stream>>>(x, xb, 2097152);
  cvt_bf16<<<6144, 256, 0, stream>>>(wq, wq_b, 1572864);
  cvt_bf16<<<1152, 256, 0, stream>>>(wkv_a, wkva_b, 294912);
  cvt_bf16<<<2048, 256, 0, stream>>>(wkv_b, wkvb_b, 524288);
  cvt_bf16<<<4096, 256, 0, stream>>>(wo, wo_b, 1048576);
  build_wnt<<<4096, 256, 0, stream>>>(wkv_b, wn_t);

  // q = x @ wq^T  -> q_buf [4096 x 3072]
  gemm_bt<uint16_t><<<dim3(24, 32, 1), 256, 0, stream>>>(xb, 2048, 0, wq_b, 2048, 0, q_buf, 3072, 0, 3072, 2048);
  // kv_full = x @ wkv_a^T -> kv_buf [4096 x 576]
  gemm_bt<uint16_t><<<dim3(5, 32, 1), 256, 0, stream>>>(xb, 2048, 0, wkva_b, 2048, 0, kv_buf, 576, 0, 576, 2048);

  rope_q<<<8192, 256, 0, stream>>>(q_buf, fcos, fsin, q_lat);
  kv_build<<<64, 256, 0, stream>>>(kv_buf, kvnw, fcos, fsin, k_lat, v_t);
  repack_kv<<<128, 256, 0, stream>>>(k_lat, v_t, k_f, v_f);

  // q_abs per head: q_nope @ wkv_b_nope^T -> q_lat[..., :512]
  gemm_bt<uint16_t><<<dim3(4, 32, 16), 256, 0, stream>>>(q_buf, 3072, 192, wn_t, 128, 65536,
                                                         q_lat, 9216, 576, 512, 128);

  flash_attn2<<<dim3(16, 32), 512, 0, stream>>>(q_lat, k_f, v_f, o_head);

  // o2 per head: o_head @ wkv_b_v^T -> o2 [4096 x 2048]
  gemm_bt<uint16_t><<<dim3(1, 32, 16), 256, 0, stream>>>(o_head, 8192, 512, wkvb_b + 65536, 512, 131072,
                                                         o2, 2048, 128, 128, 512);
  // out = o2 @ wo^T (fp32 output)
  gemm_bt<float><<<dim3(16, 32, 1), 256, 0, stream>>>(o2, 2048, 0, wo_b, 2048, 0, out, 2048, 0, 2048, 2048);
}